// Round 1
// baseline (166.640 us; speedup 1.0000x reference)
//
#include <hip/hip_runtime.h>

// Problem constants
#define H   16
#define E   300
#define D   768
#define HD  48
#define NN  4
#define QL  64
#define KL  64
#define NH  (NN*H)        // 64
#define NCHUNK 8
#define ECH 38            // ceil(300/8)

// Workspace float offsets
#define OFF_QP 0
#define OFF_KP (OFF_QP + NN*QL*D)         // 196608
#define OFF_VP (OFF_KP + KL*D)            // 245760
#define OFF_A  (OFF_VP + KL*D)            // 294912  A[nh][e][q]
#define OFF_B  (OFF_A + NH*E*QL)          // 1523712 B[nh][k][q]
#define OFF_S  (OFF_B + NH*KL*QL)         // 1785856 Spart[chunk][nh][k][q]
// end = OFF_S + NCHUNK*NH*KL*QL = 3883008 floats (~15.5 MB)

// ---------------------------------------------------------------------------
// Kernel 1: QKV projections.  rows: Q=256, K=64, V=64.  BM=16, BN=64, BK=64.
// grid (12 col tiles, 24 row tiles), 256 threads, 2x2 thread tile.
// ---------------------------------------------------------------------------
__global__ __launch_bounds__(256) void proj_kernel(
    const float* __restrict__ qin, const float* __restrict__ kin, const float* __restrict__ vin,
    const float* __restrict__ Wq, const float* __restrict__ bq,
    const float* __restrict__ Wk, const float* __restrict__ bk,
    const float* __restrict__ Wv, const float* __restrict__ bv,
    float* __restrict__ ws)
{
    const int ct0 = blockIdx.x * 64;
    const int rt  = blockIdx.y;
    const float *X, *W, *bias; float* out; int row0;
    if (rt < 16)      { X = qin; W = Wq; bias = bq; out = ws + OFF_QP; row0 = rt * 16; }
    else if (rt < 20) { X = kin; W = Wk; bias = bk; out = ws + OFF_KP; row0 = (rt - 16) * 16; }
    else              { X = vin; W = Wv; bias = bv; out = ws + OFF_VP; row0 = (rt - 20) * 16; }

    __shared__ float Xs[64][18];   // [dk][row], transposed, padded
    __shared__ float Ws[64][64];   // [dk][col]

    const int tid = threadIdx.x;
    const int r0 = (tid >> 5) * 2;   // 0..14
    const int c0 = (tid & 31) * 2;   // 0..62
    float acc00 = 0.f, acc01 = 0.f, acc10 = 0.f, acc11 = 0.f;

    for (int kk = 0; kk < D; kk += 64) {
        {   // stage X tile: 16 rows x 64 dk
            const int row = tid >> 4;            // 0..15
            const int dk0 = (tid & 15) * 4;
            const float4 xv = *(const float4*)(X + (row0 + row) * D + kk + dk0);
            Xs[dk0 + 0][row] = xv.x; Xs[dk0 + 1][row] = xv.y;
            Xs[dk0 + 2][row] = xv.z; Xs[dk0 + 3][row] = xv.w;
        }
        #pragma unroll
        for (int i = 0; i < 4; i++) {            // stage W tile: 64 dk x 64 cols
            const int idx = i * 256 + tid;       // 0..1023 (x4 floats)
            const int dk = idx >> 4;
            const int c  = (idx & 15) * 4;
            *(float4*)&Ws[dk][c] = *(const float4*)(W + (kk + dk) * D + ct0 + c);
        }
        __syncthreads();
        #pragma unroll 8
        for (int dk = 0; dk < 64; dk++) {
            const float x0 = Xs[dk][r0], x1 = Xs[dk][r0 + 1];
            const float w0 = Ws[dk][c0], w1 = Ws[dk][c0 + 1];
            acc00 += x0 * w0; acc01 += x0 * w1;
            acc10 += x1 * w0; acc11 += x1 * w1;
        }
        __syncthreads();
    }
    const float b0 = bias[ct0 + c0], b1 = bias[ct0 + c0 + 1];
    out[(row0 + r0    ) * D + ct0 + c0    ] = acc00 + b0;
    out[(row0 + r0    ) * D + ct0 + c0 + 1] = acc01 + b1;
    out[(row0 + r0 + 1) * D + ct0 + c0    ] = acc10 + b0;
    out[(row0 + r0 + 1) * D + ct0 + c0 + 1] = acc11 + b1;
}

// ---------------------------------------------------------------------------
// Kernel 2: A[nh][e][q] = mem[e,h,:]·Q[n,q,h,:]  and  B[nh][k][q] = K[k,h,:]·Q[n,q,h,:]
// Combined row space: rows 0..299 -> memory e, 300..363 -> K k.
// grid (64 nh, 6 row-chunks of 64), 256 threads, 4x4 thread tile over (row,q).
// ---------------------------------------------------------------------------
__global__ __launch_bounds__(256) void ab_kernel(
    const float* __restrict__ memo, float* __restrict__ ws)
{
    const int nh = blockIdx.x;
    const int n = nh >> 4, h = nh & 15;
    const int rc = blockIdx.y;               // 0..5
    const float* Qp = ws + OFF_QP;
    const float* Kp = ws + OFF_KP;
    float* A = ws + OFF_A;
    float* B = ws + OFF_B;

    __shared__ float Qs[QL][50];
    __shared__ float Rs[64][50];

    const int tid = threadIdx.x;
    for (int l = tid; l < QL * HD; l += 256) {           // stage Q slice (64x48)
        const int qq = l / HD, d = l % HD;
        Qs[qq][d] = Qp[(n * QL + qq) * D + h * HD + d];
    }
    for (int l = tid; l < 64 * HD; l += 256) {           // stage 64 combined rows
        const int r = l / HD, d = l % HD;
        const int rr = rc * 64 + r;
        float val = 0.f;
        if (rr < E)            val = memo[(rr * H + h) * HD + d];
        else if (rr < E + KL)  val = Kp[(rr - E) * D + h * HD + d];
        Rs[r][d] = val;
    }
    __syncthreads();

    const int rloc = (tid >> 4) * 4;   // 0..60
    const int q0   = (tid & 15) * 4;   // 0..60
    float acc[4][4] = {};
    for (int d = 0; d < HD; d += 2) {
        float2 ar[4], aq[4];
        #pragma unroll
        for (int i = 0; i < 4; i++) ar[i] = *(const float2*)&Rs[rloc + i][d];
        #pragma unroll
        for (int j = 0; j < 4; j++) aq[j] = *(const float2*)&Qs[q0 + j][d];
        #pragma unroll
        for (int i = 0; i < 4; i++)
            #pragma unroll
            for (int j = 0; j < 4; j++)
                acc[i][j] += ar[i].x * aq[j].x + ar[i].y * aq[j].y;
    }
    #pragma unroll
    for (int i = 0; i < 4; i++) {
        const int rr = rc * 64 + rloc + i;
        #pragma unroll
        for (int j = 0; j < 4; j++) {
            if (rr < E)           A[(nh * E + rr) * QL + q0 + j] = acc[i][j];
            else if (rr < E + KL) B[(nh * KL + (rr - E)) * QL + q0 + j] = acc[i][j];
        }
    }
}

// ---------------------------------------------------------------------------
// Kernel 3: the fused core.  Per (nh, e-chunk):
//   M_e[k,q] = relu(A[e,q] + B[k,q]);  T_e[k] = sum_q M_e;  S[k,q] += M_e*T_e
// thread = (k = tid>>2, q-group = tid&3 -> 16 q's).  T via quad shfl_xor.
// grid 512 = 64 nh x 8 e-chunks writing S partials.
// ---------------------------------------------------------------------------
__global__ __launch_bounds__(256) void main_kernel(float* __restrict__ ws)
{
    const int bx = blockIdx.x;
    const int nh = bx & 63, chunk = bx >> 6;
    const int e0 = chunk * ECH;
    const int e1 = (e0 + ECH < E) ? (e0 + ECH) : E;
    const float* Ab = ws + OFF_A + nh * E * QL;
    const float* Bb = ws + OFF_B + nh * KL * QL;
    float* Sb = ws + OFF_S + (chunk * NH + nh) * KL * QL;

    const int tid = threadIdx.x;
    const int k  = tid >> 2;
    const int q0 = (tid & 3) * 16;

    float4 b[4], s[4];
    #pragma unroll
    for (int j = 0; j < 4; j++) {
        b[j] = *(const float4*)(Bb + k * QL + q0 + j * 4);
        s[j] = make_float4(0.f, 0.f, 0.f, 0.f);
    }
    for (int e = e0; e < e1; e++) {
        const float* Ar = Ab + e * QL + q0;
        float4 m[4];
        float p = 0.f;
        #pragma unroll
        for (int j = 0; j < 4; j++) {
            const float4 a = *(const float4*)(Ar + j * 4);
            m[j].x = fmaxf(a.x + b[j].x, 0.f);
            m[j].y = fmaxf(a.y + b[j].y, 0.f);
            m[j].z = fmaxf(a.z + b[j].z, 0.f);
            m[j].w = fmaxf(a.w + b[j].w, 0.f);
            p += (m[j].x + m[j].y) + (m[j].z + m[j].w);
        }
        p += __shfl_xor(p, 1);
        p += __shfl_xor(p, 2);       // p = T_e[k] (full sum over 64 q)
        #pragma unroll
        for (int j = 0; j < 4; j++) {
            s[j].x += m[j].x * p;
            s[j].y += m[j].y * p;
            s[j].z += m[j].z * p;
            s[j].w += m[j].w * p;
        }
    }
    #pragma unroll
    for (int j = 0; j < 4; j++)
        *(float4*)(Sb + k * QL + q0 + j * 4) = s[j];
}

// ---------------------------------------------------------------------------
// Kernel 4: S = sum of partials;  out[n,q,h,d] = sum_k S[k,q] * V[k,h,d]
// grid 256 = 64 nh x 4 q-quarters, 256 threads, 3 outputs (d) per thread.
// ---------------------------------------------------------------------------
__global__ __launch_bounds__(256) void out_kernel(
    const float* __restrict__ ws_c, float* __restrict__ outp)
{
    const int bx = blockIdx.x;
    const int nh = bx & 63, qq = bx >> 6;
    const int n = nh >> 4, h = nh & 15;
    const int q0 = qq * 16;
    const float* Spart = ws_c + OFF_S;
    const float* Vp = ws_c + OFF_VP;

    __shared__ float S_l[KL][16];
    __shared__ float V_l[KL][HD + 1];

    const int tid = threadIdx.x;
    for (int ci = tid; ci < KL * 16; ci += 256) {        // sum 8 partials
        const int k = ci >> 4, qi = ci & 15;
        float sum = 0.f;
        #pragma unroll
        for (int c = 0; c < NCHUNK; c++)
            sum += Spart[(c * NH + nh) * KL * QL + k * QL + q0 + qi];
        S_l[k][qi] = sum;
    }
    for (int l = tid; l < KL * HD; l += 256) {           // stage V slice
        const int k = l / HD, d = l % HD;
        V_l[k][d] = Vp[k * D + h * HD + d];
    }
    __syncthreads();

    const int qi = tid >> 4;          // 0..15
    const int d0 = (tid & 15) * 3;    // 0..45
    float a0 = 0.f, a1 = 0.f, a2 = 0.f;
    #pragma unroll 8
    for (int k = 0; k < KL; k++) {
        const float sv = S_l[k][qi];
        a0 += sv * V_l[k][d0 + 0];
        a1 += sv * V_l[k][d0 + 1];
        a2 += sv * V_l[k][d0 + 2];
    }
    float* orow = outp + (n * QL + q0 + qi) * D + h * HD + d0;
    orow[0] = a0; orow[1] = a1; orow[2] = a2;
}

// ---------------------------------------------------------------------------
extern "C" void kernel_launch(void* const* d_in, const int* in_sizes, int n_in,
                              void* d_out, int out_size, void* d_ws, size_t ws_size,
                              hipStream_t stream)
{
    const float* q    = (const float*)d_in[0];
    const float* k    = (const float*)d_in[1];
    const float* v    = (const float*)d_in[2];
    const float* Wq   = (const float*)d_in[3];
    const float* bq   = (const float*)d_in[4];
    const float* Wk   = (const float*)d_in[5];
    const float* bk   = (const float*)d_in[6];
    const float* Wv   = (const float*)d_in[7];
    const float* bv   = (const float*)d_in[8];
    const float* memo = (const float*)d_in[9];
    float* ws   = (float*)d_ws;
    float* outp = (float*)d_out;

    hipLaunchKernelGGL(proj_kernel, dim3(12, 24), dim3(256), 0, stream,
                       q, k, v, Wq, bq, Wk, bk, Wv, bv, ws);
    hipLaunchKernelGGL(ab_kernel, dim3(64, 6), dim3(256), 0, stream, memo, ws);
    hipLaunchKernelGGL(main_kernel, dim3(512), dim3(256), 0, stream, ws);
    hipLaunchKernelGGL(out_kernel, dim3(256), dim3(256), 0, stream, ws, outp);
}